// Round 6
// baseline (524.233 us; speedup 1.0000x reference)
//
#include <hip/hip_runtime.h>
#include <hip/hip_bf16.h>

typedef __hip_bfloat16 bf16;
typedef __attribute__((ext_vector_type(8))) short short8;
typedef __attribute__((ext_vector_type(4))) float f32x4;

// ---------- helpers ----------
static __device__ __forceinline__ float bfbits2f(short s) {
    return __uint_as_float(((unsigned int)(unsigned short)s) << 16);
}
static __device__ __forceinline__ bf16 f2bf(float v) { return __float2bfloat16(v); }
static __device__ __forceinline__ short f2bfbits(float f) {
    bf16 h = __float2bfloat16(f);
    return *reinterpret_cast<short*>(&h);
}

// ======================================================================
// prep: xy fp32->bf16 cast | weight casts | PE weight transpose | zeroing
// ======================================================================
struct PrepArgs {
    const float *x, *y; bf16 *xb, *yb;
    const float* wsrc[10]; bf16* wdst[10]; int wblk[10];
    const float *pw1, *pw2; float *t1, *t2;
    float4* zero;                       // 34*256 float4 = 139264 B (gram+norm2)
};

__launch_bounds__(256)
__global__ void prep_kernel(PrepArgs a)
{
    int blk = blockIdx.x, tid = threadIdx.x;
    if (blk < 8192) {
        int t = blk * 256 + tid;
        int which = t >> 20;
        size_t i = (size_t)(t & 1048575) * 8;
        const float4* s = (const float4*)((which ? a.y : a.x) + i);
        float4 u = s[0], v = s[1];
        short8 p;
        p[0] = f2bfbits(u.x); p[1] = f2bfbits(u.y); p[2] = f2bfbits(u.z); p[3] = f2bfbits(u.w);
        p[4] = f2bfbits(v.x); p[5] = f2bfbits(v.y); p[6] = f2bfbits(v.z); p[7] = f2bfbits(v.w);
        *(short8*)((which ? a.yb : a.xb) + i) = p;
    } else if (blk < 8960) {
        int b = blk - 8192;
        int ai = 0, base = 0;
        while (ai < 9 && b >= base + a.wblk[ai]) { base += a.wblk[ai]; ++ai; }
        size_t i = ((size_t)(b - base) * 256 + tid) * 4;
        const float4 v = *(const float4*)(a.wsrc[ai] + i);
        bf16* d = a.wdst[ai] + i;
        d[0] = f2bf(v.x); d[1] = f2bf(v.y); d[2] = f2bf(v.z); d[3] = f2bf(v.w);
    } else if (blk < 8978) {
        int t = (blk - 8960) * 256 + tid;
        if (t < 4608) {
            int which = t >= 2304;
            int i = which ? t - 2304 : t;
            int c = i / 9, k = i % 9;
            (which ? a.t2 : a.t1)[k * 256 + c] = (which ? a.pw2 : a.pw1)[i];
        }
    } else {
        int i = (blk - 8978) * 256 + tid;
        a.zero[i] = make_float4(0.f, 0.f, 0.f, 0.f);
    }
}

// ======================================================================
// A-tile global -> LDS staging (16B, pre-swizzled source; linear LDS dest)
// 512 threads stage 128 rows x 32 k (8 KB)
// ======================================================================
static __device__ __forceinline__ void stageA(const bf16* __restrict__ g,
                                              char* dst, int tid, long r0, int k0)
{
    int row = tid >> 2;
    int q = (tid & 3) * 16;
    int srcq = q ^ (((row >> 1) & 3) << 4);
    const char* gsrc = (const char*)(g + (size_t)(r0 + row) * 256 + k0) + srcq;
    char* ldst = dst + ((tid >> 6) << 10);
    __builtin_amdgcn_global_load_lds(
        (const __attribute__((address_space(1))) unsigned int*)gsrc,
        (__attribute__((address_space(3))) unsigned int*)ldst, 16, 0, 0);
}

// h buffer: [128 rows][256 cols] bf16, XOR-swizzled
static __device__ __forceinline__ int h_off2(int r, int c)
{
    return r * 512 + ((c * 2) ^ ((r & 7) << 4));
}

// ======================================================================
// Fused 2-layer MLP; weight-set / A / outputs selected by blockIdx.x.
// stage1: A(128 x K1) @ B1(256 x K1)^T + b1 -> lrelu -> h (LDS)
//   A staged via global_load_lds; B1 frags read global->regs (L2-hot),
//   depth-1 ping-pong prefetch, fully unrolled (static reg indexing).
// stage2: h @ W2(256x256)^T, 8-wave x 32-col, W2 reg prefetch.
// epilogue via LDS re-transpose -> coalesced short8 stores.
// outT[sel] != 0: channel-major transposed store + per-col sumsq -> nrm.
// ======================================================================
struct MlpArgs {
    const bf16* A0[3];
    const bf16* B1[3]; const float* b1[3];
    const bf16* W2[3]; const float* b2[3];
    bf16* outb[3]; bf16* outT[3]; float* nrm[3];
};

template<int K1, bool CONCAT>
__launch_bounds__(512, 2)
__global__ void mlp_kernel(const bf16* __restrict__ A1c, MlpArgs args)
{
    __shared__ __align__(16) char lds[66560];
    int tid = threadIdx.x;
    int lane = tid & 63, wid = tid >> 6;
    int c16 = lane & 15, kg = lane >> 4;
    int wr = wid >> 2, wc = wid & 3;            // stage1: 2x4 waves, 64x64 tiles
    int sel = blockIdx.x;
    long m0 = (long)blockIdx.y * 128;
    const bf16* A0 = args.A0[sel];
    const bf16* B1p = args.B1[sel];
    const bf16* W2p = args.W2[sel];
    char* Abuf = lds;                            // 2 x 8192

    f32x4 acc[4][4];
#pragma unroll
    for (int i = 0; i < 4; ++i)
#pragma unroll
        for (int j = 0; j < 4; ++j) acc[i][j] = (f32x4){0.f, 0.f, 0.f, 0.f};

    // B1 row pointers (row = output col), 64B/line fully used by 4 kg-lanes
    const bf16* brow[4];
#pragma unroll
    for (int ni = 0; ni < 4; ++ni)
        brow[ni] = B1p + (size_t)(wc * 64 + ni * 16 + c16) * K1 + kg * 8;

    stageA(A0, Abuf, tid, m0, 0);

    int kb = kg * 16;
    int offa[4];
#pragma unroll
    for (int mi = 0; mi < 4; ++mi) {
        int row = wr * 64 + mi * 16 + c16;
        offa[mi] = row * 64 + (kb ^ (((row >> 1) & 3) << 4));
    }

    short8 bfrag[2][4];
#pragma unroll
    for (int ni = 0; ni < 4; ++ni) bfrag[0][ni] = *(const short8*)(brow[ni]);

    constexpr int NT1 = K1 / 32;
#pragma unroll
    for (int kt = 0; kt < NT1; ++kt) {
        __syncthreads();
        if (kt + 1 < NT1) {
            int k0 = (kt + 1) * 32;
            const bf16* As = A0; int kk = k0;
            if (CONCAT && k0 >= 256) { As = A1c; kk = k0 - 256; }
            stageA(As, Abuf + ((kt & 1) ^ 1) * 8192, tid, m0, kk);
#pragma unroll
            for (int ni = 0; ni < 4; ++ni)
                bfrag[(kt + 1) & 1][ni] = *(const short8*)(brow[ni] + (kt + 1) * 32);
        }
        const char* As = Abuf + (kt & 1) * 8192;
        short8 af[4];
#pragma unroll
        for (int mi = 0; mi < 4; ++mi) af[mi] = *(const short8*)(As + offa[mi]);
#pragma unroll
        for (int mi = 0; mi < 4; ++mi)
#pragma unroll
            for (int ni = 0; ni < 4; ++ni)
                acc[mi][ni] = __builtin_amdgcn_mfma_f32_16x16x32_bf16(af[mi], bfrag[kt & 1][ni], acc[mi][ni], 0, 0, 0);
    }

    // ---- W2 kc=0 prefetch ----
    int co0 = wid * 32 + c16;
    short8 wf[2][2];
    wf[0][0] = *(const short8*)(W2p + (size_t)co0 * 256 + kg * 8);
    wf[0][1] = *(const short8*)(W2p + (size_t)(co0 + 16) * 256 + kg * 8);

    float bv1[4];
#pragma unroll
    for (int ni = 0; ni < 4; ++ni) bv1[ni] = args.b1[sel][wc * 64 + ni * 16 + c16];
    __syncthreads();   // stage1 A reads done; lds becomes h
#pragma unroll
    for (int mi = 0; mi < 4; ++mi)
#pragma unroll
        for (int ni = 0; ni < 4; ++ni) {
            int c = wc * 64 + ni * 16 + c16;
#pragma unroll
            for (int j = 0; j < 4; ++j) {
                int r = wr * 64 + mi * 16 + kg * 4 + j;
                float v = acc[mi][ni][j] + bv1[ni];
                v = v > 0.f ? v : 0.01f * v;
                *(bf16*)(lds + h_off2(r, c)) = f2bf(v);
            }
        }
    __syncthreads();

    // ---- stage2: wave = 32 cols x 128 rows ----
    f32x4 acc2[8][2];
#pragma unroll
    for (int i = 0; i < 8; ++i) {
        acc2[i][0] = (f32x4){0.f, 0.f, 0.f, 0.f};
        acc2[i][1] = (f32x4){0.f, 0.f, 0.f, 0.f};
    }
#pragma unroll
    for (int kc = 0; kc < 8; ++kc) {
        if (kc < 7) {
            wf[(kc + 1) & 1][0] = *(const short8*)(W2p + (size_t)co0 * 256 + (kc + 1) * 32 + kg * 8);
            wf[(kc + 1) & 1][1] = *(const short8*)(W2p + (size_t)(co0 + 16) * 256 + (kc + 1) * 32 + kg * 8);
        }
#pragma unroll
        for (int mi = 0; mi < 8; ++mi) {
            short8 a2 = *(const short8*)(lds + h_off2(mi * 16 + c16, kc * 32 + kg * 8));
            acc2[mi][0] = __builtin_amdgcn_mfma_f32_16x16x32_bf16(a2, wf[kc & 1][0], acc2[mi][0], 0, 0, 0);
            acc2[mi][1] = __builtin_amdgcn_mfma_f32_16x16x32_bf16(a2, wf[kc & 1][1], acc2[mi][1], 0, 0, 0);
        }
    }

    // ---- epilogue: LDS re-transpose -> coalesced stores ----
    bool trans = args.outT[sel] != nullptr;
    const float* b2p = args.b2[sel];
    float vsq[2] = {0.f, 0.f};
    __syncthreads();   // h dead
    if (trans) {
#pragma unroll
        for (int mi = 0; mi < 8; ++mi)
#pragma unroll
            for (int j2 = 0; j2 < 2; ++j2) {
                int col = co0 + j2 * 16;
#pragma unroll
                for (int j = 0; j < 4; ++j) {
                    float v = acc2[mi][j2][j];
                    vsq[j2] += v * v;
                    int row = mi * 16 + kg * 4 + j;
                    *(bf16*)(lds + col * 256 + ((row * 2) ^ ((col & 7) << 4))) = f2bf(v);
                }
            }
    } else {
        float bvo[2];
        bvo[0] = b2p ? b2p[co0] : 0.f;
        bvo[1] = b2p ? b2p[co0 + 16] : 0.f;
#pragma unroll
        for (int mi = 0; mi < 8; ++mi)
#pragma unroll
            for (int j2 = 0; j2 < 2; ++j2) {
                int col = co0 + j2 * 16;
#pragma unroll
                for (int j = 0; j < 4; ++j) {
                    int row = mi * 16 + kg * 4 + j;
                    *(bf16*)(lds + h_off2(row, col)) = f2bf(acc2[mi][j2][j] + bvo[j2]);
                }
            }
    }
    __syncthreads();
    if (trans) {
        bf16* dst = args.outT[sel];
#pragma unroll
        for (int i = 0; i < 8; ++i) {
            int g = i * 512 + tid;
            int col = g >> 4, rc = g & 15;
            short8 vv = *(const short8*)(lds + col * 256 + ((rc ^ (col & 7)) << 4));
            *(short8*)(dst + (size_t)col * 65536 + m0 + rc * 8) = vv;
        }
        float* cs = (float*)(lds + 65536);
        if (tid < 256) cs[tid] = 0.f;
        __syncthreads();
        atomicAdd(&cs[co0], vsq[0]);
        atomicAdd(&cs[co0 + 16], vsq[1]);
        __syncthreads();
        if (tid < 256)
            atomicAdd(args.nrm[sel] + (int)(m0 >> 14) * 256 + tid, cs[tid]);
    } else {
        bf16* dst = args.outb[sel];
#pragma unroll
        for (int i = 0; i < 8; ++i) {
            int g = i * 512 + tid;
            int row = g >> 5, cc = g & 31;
            short8 vv = *(const short8*)(lds + row * 512 + ((cc ^ (row & 7)) << 4));
            *(short8*)(dst + (size_t)(m0 + row) * 256 + cc * 8) = vv;
        }
    }
}

// ======================================================================
// projconv: out[row,256] = V @ PW(quarter)^T + bias_total + dwconv2(ctmp)
// block = 128 rows = one image line (y) of one quarter.
// GEMM (direct-B regs) -> acc; per 64-row half: acc -> LDS f32 -> conv+add
// -> single coalesced fp32 store of d_out.
// ======================================================================
__launch_bounds__(512, 2)
__global__ void projconv_kernel(const bf16* __restrict__ vbuf, const bf16* __restrict__ PW,
                                const bf16* __restrict__ ctmp,
                                const float* __restrict__ px_b, const float* __restrict__ py_b,
                                const float* __restrict__ peT2, const float* __restrict__ pe_b2,
                                float* __restrict__ outf)
{
    __shared__ __align__(16) char lds[76800];
    float* ldsF = (float*)lds;                       // [64][260] f32 (66560 B)
    float* ldsW = (float*)(lds + 66560);             // [9][256]  f32 (9216 B)
    float* ldsB = (float*)(lds + 75776);             // [256]     f32 (1024 B)
    int tid = threadIdx.x;
    int lane = tid & 63, wid = tid >> 6;
    int c16 = lane & 15, kg = lane >> 4;
    int wr = wid >> 2, wc = wid & 3;
    long m0 = (long)blockIdx.y * 128;
    int quarter = (int)(m0 >> 14);
    int y = (int)((m0 & 16383) >> 7);
    char* Abuf = lds;                                // 2 x 8192 (GEMM phase only)

    f32x4 acc[4][4];
#pragma unroll
    for (int i = 0; i < 4; ++i)
#pragma unroll
        for (int j = 0; j < 4; ++j) acc[i][j] = (f32x4){0.f, 0.f, 0.f, 0.f};

    const bf16* Bq = PW + (size_t)quarter * 65536;
    const bf16* brow[4];
#pragma unroll
    for (int ni = 0; ni < 4; ++ni)
        brow[ni] = Bq + (size_t)(wc * 64 + ni * 16 + c16) * 256 + kg * 8;

    stageA(vbuf, Abuf, tid, m0, 0);

    // conv tables (region disjoint from staging)
#pragma unroll
    for (int i = 0; i < 5; ++i) {
        int idx = i * 512 + tid;
        if (idx < 2304) ldsW[idx] = peT2[idx];
    }
    if (tid < 256) ldsB[tid] = (quarter < 2 ? px_b : py_b)[tid] + pe_b2[tid];

    int kb = kg * 16;
    int offa[4];
#pragma unroll
    for (int mi = 0; mi < 4; ++mi) {
        int row = wr * 64 + mi * 16 + c16;
        offa[mi] = row * 64 + (kb ^ (((row >> 1) & 3) << 4));
    }

    short8 bfrag[2][4];
#pragma unroll
    for (int ni = 0; ni < 4; ++ni) bfrag[0][ni] = *(const short8*)(brow[ni]);

#pragma unroll
    for (int kt = 0; kt < 8; ++kt) {
        __syncthreads();
        if (kt + 1 < 8) {
            stageA(vbuf, Abuf + ((kt & 1) ^ 1) * 8192, tid, m0, (kt + 1) * 32);
#pragma unroll
            for (int ni = 0; ni < 4; ++ni)
                bfrag[(kt + 1) & 1][ni] = *(const short8*)(brow[ni] + (kt + 1) * 32);
        }
        const char* As = Abuf + (kt & 1) * 8192;
        short8 af[4];
#pragma unroll
        for (int mi = 0; mi < 4; ++mi) af[mi] = *(const short8*)(As + offa[mi]);
#pragma unroll
        for (int mi = 0; mi < 4; ++mi)
#pragma unroll
            for (int ni = 0; ni < 4; ++ni)
                acc[mi][ni] = __builtin_amdgcn_mfma_f32_16x16x32_bf16(af[mi], bfrag[kt & 1][ni], acc[mi][ni], 0, 0, 0);
    }

    const bf16* cbase = ctmp + (((size_t)quarter << 14) << 8);
#pragma unroll
    for (int hh = 0; hh < 2; ++hh) {
        __syncthreads();   // prev phase (GEMM A-reads / prev conv) done
        if (wr == hh) {
#pragma unroll
            for (int mi = 0; mi < 4; ++mi)
#pragma unroll
                for (int ni = 0; ni < 4; ++ni) {
                    int col = wc * 64 + ni * 16 + c16;
#pragma unroll
                    for (int j = 0; j < 4; ++j)
                        ldsF[(mi * 16 + kg * 4 + j) * 260 + col] = acc[mi][ni][j];
                }
        }
        __syncthreads();
#pragma unroll
        for (int pass = 0; pass < 4; ++pass) {
            int idx = pass * 512 + tid;          // 0..2047
            int cg = idx & 31, c0 = cg * 8;
            int xl = idx >> 5;                   // 0..63
            int x = hh * 64 + xl;
            float a8[8];
#pragma unroll
            for (int j = 0; j < 8; ++j) a8[j] = ldsB[c0 + j];
#pragma unroll
            for (int dy = -1; dy <= 1; ++dy) {
                int yy = y + dy;
                if (yy < 0 || yy > 127) continue;
#pragma unroll
                for (int dx = -1; dx <= 1; ++dx) {
                    int xx = x + dx;
                    if (xx < 0 || xx > 127) continue;
                    short8 v = *(const short8*)(cbase + (size_t)((yy << 7) + xx) * 256 + c0);
                    const float* wt = ldsW + ((dy + 1) * 3 + dx + 1) * 256 + c0;
#pragma unroll
                    for (int j = 0; j < 8; ++j) a8[j] += wt[j] * bfbits2f(v[j]);
                }
            }
            const float* pf = ldsF + xl * 260 + c0;
#pragma unroll
            for (int j = 0; j < 8; ++j) a8[j] += pf[j];
            float4 o0 = make_float4(a8[0], a8[1], a8[2], a8[3]);
            float4 o1 = make_float4(a8[4], a8[5], a8[6], a8[7]);
            float4* op = (float4*)(outf + (size_t)(m0 + x) * 256 + c0);
            op[0] = o0; op[1] = o1;
        }
    }
}

// ======================================================================
// MFMA Gram: gram[pair][b][h][d][e]
// ======================================================================
__launch_bounds__(256)
__global__ void gram_mfma_kernel(const bf16* __restrict__ qT, const bf16* __restrict__ kT,
                                 float* __restrict__ gram)
{
    __shared__ float g[1024];
    int bid = blockIdx.x;
    int ns = bid & 15, h = (bid >> 4) & 7, b = (bid >> 7) & 1, pair = bid >> 8;
    int tid = threadIdx.x;
    int lane = tid & 63, w = tid >> 6;
    long krow = pair ? (long)b * 16384 : (long)(32768 + b * 16384);
    long qrow = pair ? (long)(32768 + b * 16384) : (long)b * 16384;
    long nb = (long)ns * 1024 + w * 256 + (lane >> 4) * 8;
    const bf16* Kp = kT + krow + nb;
    const bf16* Qp = qT + qrow + nb;
    int ch = h * 32 + (lane & 15);

    f32x4 acc[2][2];
#pragma unroll
    for (int i = 0; i < 2; ++i)
#pragma unroll
        for (int j = 0; j < 2; ++j) acc[i][j] = (f32x4){0.f, 0.f, 0.f, 0.f};

    for (int it = 0; it < 8; ++it) {
        short8 af[2], bfr[2];
#pragma unroll
        for (int mi = 0; mi < 2; ++mi)
            af[mi] = *(const short8*)(Kp + (size_t)(ch + mi * 16) * 65536 + it * 32);
#pragma unroll
        for (int ni = 0; ni < 2; ++ni)
            bfr[ni] = *(const short8*)(Qp + (size_t)(ch + ni * 16) * 65536 + it * 32);
#pragma unroll
        for (int mi = 0; mi < 2; ++mi)
#pragma unroll
            for (int ni = 0; ni < 2; ++ni)
                acc[mi][ni] = __builtin_amdgcn_mfma_f32_16x16x32_bf16(af[mi], bfr[ni], acc[mi][ni], 0, 0, 0);
    }

#pragma unroll
    for (int k = 0; k < 4; ++k) g[tid + k * 256] = 0.f;
    __syncthreads();
#pragma unroll
    for (int mi = 0; mi < 2; ++mi)
#pragma unroll
        for (int ni = 0; ni < 2; ++ni) {
            int e = ni * 16 + (lane & 15);
#pragma unroll
            for (int j = 0; j < 4; ++j) {
                int d = mi * 16 + (lane >> 4) * 4 + j;
                atomicAdd(&g[d * 32 + e], acc[mi][ni][j]);
            }
        }
    __syncthreads();
    float* gp = gram + ((size_t)((pair * 2 + b) * 8 + h)) * 1024;
#pragma unroll
    for (int k = 0; k < 4; ++k)
        atomicAdd(gp + tid + k * 256, g[tid + k * 256]);
}

// ======================================================================
// softmax + fold attention into project-out weights
// ======================================================================
__launch_bounds__(256)
__global__ void attn_pw_kernel(const float* __restrict__ gram, const float* __restrict__ norm2,
                               const float* __restrict__ rsx, const float* __restrict__ rsy,
                               const float* __restrict__ pxw, const float* __restrict__ pyw,
                               bf16* __restrict__ PW)
{
    int bid = blockIdx.x;
    int h = bid & 7, b = (bid >> 3) & 1, pair = bid >> 4;
    const float* G = gram + ((size_t)((pair * 2 + b) * 8 + h)) * 1024;
    const float* nk2 = norm2 + (pair ? (4 + b) : (6 + b)) * 256 + h * 32;
    const float* nq2 = norm2 + (pair ? (2 + b) : (0 + b)) * 256 + h * 32;
    float rs = (pair ? rsy : rsx)[h];
    __shared__ float attn[32][32];
    int t = threadIdx.x;
    if (t < 32) {
        int d = t;
        float nk = fmaxf(sqrtf(nk2[d]), 1e-12f);
        float row[32];
        float mx = -3.4e38f;
#pragma unroll
        for (int e = 0; e < 32; ++e) {
            float nq = fmaxf(sqrtf(nq2[e]), 1e-12f);
            float L = G[d * 32 + e] / (nk * nq) * rs;
            row[e] = L;
            mx = fmaxf(mx, L);
        }
        float sum = 0.f;
#pragma unroll
        for (int e = 0; e < 32; ++e) { row[e] = expf(row[e] - mx); sum += row[e]; }
        float inv = 1.0f / sum;
#pragma unroll
        for (int e = 0; e < 32; ++e) attn[d][e] = row[e] * inv;
    }
    __syncthreads();
    const float* pw = pair ? pyw : pxw;
    int o = t;
    float wrow[32];
#pragma unroll
    for (int d2 = 0; d2 < 32; ++d2) wrow[d2] = pw[o * 256 + h * 32 + d2];
    bf16* dst = PW + ((size_t)(pair * 2 + b) * 256 + o) * 256 + h * 32;
#pragma unroll
    for (int e = 0; e < 32; ++e) {
        float sv = 0.f;
#pragma unroll
        for (int d2 = 0; d2 < 32; ++d2) sv += wrow[d2] * attn[d2][e];
        dst[e] = f2bf(sv);
    }
}

// ======================================================================
// depthwise 3x3 conv + exact GELU over the 4-quarter vbuf -> ctmp (bf16)
// ======================================================================
__launch_bounds__(256)
__global__ void dwconv1_kernel(const bf16* __restrict__ in, const float* __restrict__ wT,
                               const float* __restrict__ bias, bf16* __restrict__ outb)
{
    int t = blockIdx.x * 256 + threadIdx.x;   // 2048 blocks = 524288 threads
    int cg = t & 31;
    int x = (t >> 5) & 127;
    int chunk = (t >> 12) & 31;
    int img = t >> 17;                        // 0..3 quarters
    int c0 = cg * 8;

    float w[9][8];
#pragma unroll
    for (int k = 0; k < 9; ++k) {
        float4 a = *(const float4*)(wT + k * 256 + c0);
        float4 bq = *(const float4*)(wT + k * 256 + c0 + 4);
        w[k][0] = a.x; w[k][1] = a.y; w[k][2] = a.z; w[k][3] = a.w;
        w[k][4] = bq.x; w[k][5] = bq.y; w[k][6] = bq.z; w[k][7] = bq.w;
    }
    float bs[8];
    {
        float4 a = *(const float4*)(bias + c0);
        float4 bq = *(const float4*)(bias + c0 + 4);
        bs[0] = a.x; bs[1] = a.y; bs[2] = a.z; bs[3] = a.w;
        bs[4] = bq.x; bs[5] = bq.y; bs[6] = bq.z; bs[7] = bq.w;
    }
    const short8 z = (short8){0, 0, 0, 0, 0, 0, 0, 0};
    bool xm = x > 0, xp = x < 127;
    int y0 = chunk * 4;

    for (int yi = 0; yi < 4; ++yi) {
        int y = y0 + yi;
        float acc[8];
#pragma unroll
        for (int j = 0; j < 8; ++j) acc[j] = bs[j];
#pragma unroll
        for (int ky = -1; ky <= 1; ++ky) {
            int yy = y + ky;
            if (yy < 0 || yy > 127) continue;
            const bf16* rp = in + ((((size_t)img << 14) + (yy << 7) + x) << 8) + c0;
            short8 vm = xm ? *(const short8*)(rp - 256) : z;
            short8 vc = *(const short8*)(rp);
            short8 vp = xp ? *(const short8*)(rp + 256) : z;
            int k0 = (ky + 1) * 3;
#pragma unroll
            for (int j = 0; j < 8; ++j) {
                acc[j] += w[k0 + 0][j] * bfbits2f(vm[j]);
                acc[j] += w[k0 + 1][j] * bfbits2f(vc[j]);
                acc[j] += w[k0 + 2][j] * bfbits2f(vp[j]);
            }
        }
        size_t base = ((((size_t)img << 14) + (y << 7) + x) << 8) + c0;
        short8 p;
#pragma unroll
        for (int j = 0; j < 8; ++j) {
            float a = acc[j];
            a = 0.5f * a * (1.0f + erff(a * 0.70710678118654752f));
            p[j] = f2bfbits(a);
        }
        *(short8*)(outb + base) = p;
    }
}

// ======================================================================
// launch
// ======================================================================
extern "C" void kernel_launch(void* const* d_in, const int* in_sizes, int n_in,
                              void* d_out, int out_size, void* d_ws, size_t ws_size,
                              hipStream_t stream)
{
    const float* x_in  = (const float*)d_in[0];
    const float* y_in  = (const float*)d_in[1];
    const float* fx_w1 = (const float*)d_in[2];
    const float* fx_b1 = (const float*)d_in[3];
    const float* fx_w2 = (const float*)d_in[4];
    const float* fx_b2 = (const float*)d_in[5];
    const float* fy_w1 = (const float*)d_in[6];
    const float* fy_b1 = (const float*)d_in[7];
    const float* fy_w2 = (const float*)d_in[8];
    const float* fy_b2 = (const float*)d_in[9];
    const float* q_w1  = (const float*)d_in[10];
    const float* q_b1  = (const float*)d_in[11];
    const float* q_w2  = (const float*)d_in[12];
    const float* k_w1  = (const float*)d_in[13];
    const float* k_b1  = (const float*)d_in[14];
    const float* k_w2  = (const float*)d_in[15];
    const float* v_w1  = (const float*)d_in[16];
    const float* v_b1  = (const float*)d_in[17];
    const float* v_w2  = (const float*)d_in[18];
    const float* rescale_x = (const float*)d_in[19];
    const float* rescale_y = (const float*)d_in[20];
    const float* px_w  = (const float*)d_in[21];
    const float* px_b  = (const float*)d_in[22];
    const float* py_w  = (const float*)d_in[23];
    const float* py_b  = (const float*)d_in[24];
    const float* pe_w1 = (const float*)d_in[25];
    const float* pe_b1 = (const float*)d_in[26];
    const float* pe_w2 = (const float*)d_in[27];
    const float* pe_b2 = (const float*)d_in[28];

    char* ws = (char*)d_ws;
    const size_t NB = 16777216;
    bf16* xbf  = (bf16*)(ws + 0 * NB);    // [xb | yb] adjacent (65536 rows)
    bf16* ybf  = (bf16*)(ws + 1 * NB);
    bf16* fkx  = (bf16*)(ws + 2 * NB);    // [fkx | fky]; reused as ctmp after k-MLP
    bf16* fky  = (bf16*)(ws + 3 * NB);
    bf16* vbuf = (bf16*)(ws + 4 * NB);    // 65536 rows [vx_b0,vx_b1,vy_b0,vy_b1]
    bf16* qT   = (bf16*)(ws + 6 * NB);    // [256][65536] channel-major
    bf16* kT   = (bf16*)(ws + 8 * NB);
    char* wreg = ws + 10 * NB;
    bf16* w_fx1 = (bf16*)(wreg + 0);
    bf16* w_fx2 = (bf16*)(wreg + 262144);
    bf16* w_fy1 = (bf16*)(wreg + 393216);
    bf16* w_fy2 = (bf16*)(wreg + 655360);
    bf16* w_q1  = (bf16*)(wreg + 786432);
    bf16* w_q2  = (bf16*)(wreg + 917504);
    bf16* w_k1  = (bf16*)(wreg + 1048576);
    bf16* w_k2  = (bf16*)(wreg + 1179648);
    bf16* w_v1  = (bf16*)(wreg + 1310720);
    bf16* w_v2  = (bf16*)(wreg + 1441792);
    float* gram  = (float*)(wreg + 1572864);             // 128 KB
    float* norm2 = (float*)(wreg + 1572864 + 131072);    // 8 KB
    bf16* PW     = (bf16*)(wreg + 1572864 + 139264);     // 512 KB
    float* peT1  = (float*)(wreg + 1572864 + 139264 + 524288);
    float* peT2  = (float*)(wreg + 1572864 + 139264 + 524288 + 9216);
    bf16* ctmp   = fkx;                    // 65536-row conv temp (fk dead by then)

    float* outx = (float*)d_out;           // rows 0..32767 = x, 32768.. = y

    // ---- prep ----
    PrepArgs pa;
    pa.x = x_in; pa.y = y_in; pa.xb = xbf; pa.yb = ybf;
    const float* ws_src[10] = {fx_w1, fx_w2, fy_w1, fy_w2, q_w1, q_w2, k_w1, k_w2, v_w1, v_w2};
    bf16* ws_dst[10] = {w_fx1, w_fx2, w_fy1, w_fy2, w_q1, w_q2, w_k1, w_k2, w_v1, w_v2};
    int nblk[10] = {128, 64, 128, 64, 64, 64, 64, 64, 64, 64};
    for (int i = 0; i < 10; ++i) { pa.wsrc[i] = ws_src[i]; pa.wdst[i] = ws_dst[i]; pa.wblk[i] = nblk[i]; }
    pa.pw1 = pe_w1; pa.pw2 = pe_w2; pa.t1 = peT1; pa.t2 = peT2;
    pa.zero = (float4*)gram;
    prep_kernel<<<9012, 256, 0, stream>>>(pa);

    // ---- fusion MLPs (sel: fx, fy) ----
    MlpArgs fa = {};
    fa.A0[0] = xbf; fa.A0[1] = xbf;
    fa.B1[0] = w_fx1; fa.B1[1] = w_fy1; fa.b1[0] = fx_b1; fa.b1[1] = fy_b1;
    fa.W2[0] = w_fx2; fa.W2[1] = w_fy2; fa.b2[0] = fx_b2; fa.b2[1] = fy_b2;
    fa.outb[0] = fkx; fa.outb[1] = fky;
    mlp_kernel<512, true><<<dim3(2, 256), 512, 0, stream>>>(ybf, fa);

    // ---- q/v/k MLPs (sel: q, v, k) ----
    MlpArgs qa = {};
    qa.A0[0] = xbf; qa.A0[1] = xbf; qa.A0[2] = fkx;
    qa.B1[0] = w_q1; qa.B1[1] = w_v1; qa.B1[2] = w_k1;
    qa.b1[0] = q_b1; qa.b1[1] = v_b1; qa.b1[2] = k_b1;
    qa.W2[0] = w_q2; qa.W2[1] = w_v2; qa.W2[2] = w_k2;
    qa.outT[0] = qT; qa.nrm[0] = norm2;
    qa.outb[1] = vbuf;
    qa.outT[2] = kT; qa.nrm[2] = norm2 + 1024;
    mlp_kernel<256, false><<<dim3(3, 512), 512, 0, stream>>>(nullptr, qa);

    // ---- pos_emb conv1 (fk dead now; ctmp aliases it) ----
    dwconv1_kernel<<<2048, 256, 0, stream>>>(vbuf, peT1, pe_b1, ctmp);

    // ---- attention statistics ----
    gram_mfma_kernel<<<512, 256, 0, stream>>>(qT, kT, gram);
    attn_pw_kernel<<<32, 256, 0, stream>>>(gram, norm2, rescale_x, rescale_y, px_w, py_w, PW);

    // ---- project-out + conv2 + biases, single pass over d_out ----
    projconv_kernel<<<dim3(1, 512), 512, 0, stream>>>(vbuf, PW, ctmp, px_b, py_b,
                                                      peT2, pe_b2, outx);
}

// Round 7
// 406.160 us; speedup vs baseline: 1.2907x; 1.2907x over previous
//
#include <hip/hip_runtime.h>
#include <hip/hip_bf16.h>

typedef __hip_bfloat16 bf16;
typedef __attribute__((ext_vector_type(8))) short short8;
typedef __attribute__((ext_vector_type(4))) float f32x4;

// ---------- helpers ----------
static __device__ __forceinline__ float bfbits2f(short s) {
    return __uint_as_float(((unsigned int)(unsigned short)s) << 16);
}
static __device__ __forceinline__ bf16 f2bf(float v) { return __float2bfloat16(v); }
static __device__ __forceinline__ short f2bfbits(float f) {
    bf16 h = __float2bfloat16(f);
    return *reinterpret_cast<short*>(&h);
}

// ======================================================================
// prep: xy fp32->bf16 cast | weight casts | PE weight transpose | zeroing
// ======================================================================
struct PrepArgs {
    const float *x, *y; bf16 *xb, *yb;
    const float* wsrc[10]; bf16* wdst[10]; int wblk[10];
    const float *pw1, *pw2; float *t1, *t2;
    float4* zero;                       // 34*256 float4 = 139264 B (gram+norm2)
};

__launch_bounds__(256)
__global__ void prep_kernel(PrepArgs a)
{
    int blk = blockIdx.x, tid = threadIdx.x;
    if (blk < 8192) {
        int t = blk * 256 + tid;
        int which = t >> 20;
        size_t i = (size_t)(t & 1048575) * 8;
        const float4* s = (const float4*)((which ? a.y : a.x) + i);
        float4 u = s[0], v = s[1];
        short8 p;
        p[0] = f2bfbits(u.x); p[1] = f2bfbits(u.y); p[2] = f2bfbits(u.z); p[3] = f2bfbits(u.w);
        p[4] = f2bfbits(v.x); p[5] = f2bfbits(v.y); p[6] = f2bfbits(v.z); p[7] = f2bfbits(v.w);
        *(short8*)((which ? a.yb : a.xb) + i) = p;
    } else if (blk < 8960) {
        int b = blk - 8192;
        int ai = 0, base = 0;
        while (ai < 9 && b >= base + a.wblk[ai]) { base += a.wblk[ai]; ++ai; }
        size_t i = ((size_t)(b - base) * 256 + tid) * 4;
        const float4 v = *(const float4*)(a.wsrc[ai] + i);
        bf16* d = a.wdst[ai] + i;
        d[0] = f2bf(v.x); d[1] = f2bf(v.y); d[2] = f2bf(v.z); d[3] = f2bf(v.w);
    } else if (blk < 8978) {
        int t = (blk - 8960) * 256 + tid;
        if (t < 4608) {
            int which = t >= 2304;
            int i = which ? t - 2304 : t;
            int c = i / 9, k = i % 9;
            (which ? a.t2 : a.t1)[k * 256 + c] = (which ? a.pw2 : a.pw1)[i];
        }
    } else {
        int i = (blk - 8978) * 256 + tid;
        a.zero[i] = make_float4(0.f, 0.f, 0.f, 0.f);
    }
}

// ======================================================================
// global -> LDS staging (16B, pre-swizzled source; linear LDS dest)
// ======================================================================
template<int ROWS>
static __device__ __forceinline__ void stage8(const bf16* __restrict__ g, int ldk,
                                              char* dst, int tid, long r0, int k0)
{
#pragma unroll
    for (int r = 0; r < ROWS / 128; ++r) {
        int row = r * 128 + (tid >> 2);
        int q = (tid & 3) * 16;
        int srcq = q ^ (((row >> 1) & 3) << 4);
        const char* gsrc = (const char*)(g + (size_t)(r0 + row) * ldk + k0) + srcq;
        char* ldst = dst + r * 8192 + ((tid >> 6) << 10);
        __builtin_amdgcn_global_load_lds(
            (const __attribute__((address_space(1))) unsigned int*)gsrc,
            (__attribute__((address_space(3))) unsigned int*)ldst, 16, 0, 0);
    }
}

// h buffer: [128 rows][256 cols] bf16, XOR-swizzled
static __device__ __forceinline__ int h_off2(int r, int c)
{
    return r * 512 + ((c * 2) ^ ((r & 7) << 4));
}

// ======================================================================
// Fused 2-layer MLP, weight-set selected by blockIdx.x (sel). [R4-proven]
// stage1: A(128 x K1) @ B1(256 x K1)^T + b1 -> lrelu -> h (LDS)
//         A and B1 both LDS-staged via global_load_lds, double-buffered.
// stage2: h @ W2(256x256)^T, 8-wave x 32-col tiling, W2 reg prefetch.
// epilogue via LDS re-transpose -> coalesced short8 stores.
// TRANS0 && sel==0: channel-major outT + per-col sumsq -> nrm.
// ======================================================================
struct MlpArgs {
    const bf16* B1[2]; const float* b1[2];
    const bf16* W2[2]; const float* b2[2];
    bf16* outb[2]; bf16* outT[2]; float* nrm[2];
};

template<int K1, bool CONCAT, bool B2OUT, bool TRANS0>
__launch_bounds__(512, 4)
__global__ void mlp_kernel(const bf16* __restrict__ A0, const bf16* __restrict__ A1,
                           MlpArgs args)
{
    __shared__ __align__(16) char lds[66560];
    int tid = threadIdx.x;
    int lane = tid & 63, wid = tid >> 6;
    int c16 = lane & 15, kg = lane >> 4;
    int wr = wid >> 2, wc = wid & 3;            // stage1: 2x4 waves, 64x64 tiles
    int sel = blockIdx.x;
    long m0 = (long)blockIdx.y * 128;
    const bf16* B1p = args.B1[sel];
    const bf16* W2p = args.W2[sel];
    char* Abuf = lds;                            // 2 x 8192
    char* Bbuf = lds + 16384;                    // 2 x 16384

    f32x4 acc[4][4];
#pragma unroll
    for (int i = 0; i < 4; ++i)
#pragma unroll
        for (int j = 0; j < 4; ++j) acc[i][j] = (f32x4){0.f, 0.f, 0.f, 0.f};

    stage8<128>(A0, 256, Abuf, tid, m0, 0);
    stage8<256>(B1p, K1, Bbuf, tid, 0, 0);

    int kb = kg * 16;
    int offa[4], offb[4];
#pragma unroll
    for (int mi = 0; mi < 4; ++mi) {
        int row = wr * 64 + mi * 16 + c16;
        offa[mi] = row * 64 + (kb ^ (((row >> 1) & 3) << 4));
    }
#pragma unroll
    for (int ni = 0; ni < 4; ++ni) {
        int row = wc * 64 + ni * 16 + c16;
        offb[ni] = row * 64 + (kb ^ (((row >> 1) & 3) << 4));
    }

    constexpr int NT1 = K1 / 32;
#pragma unroll
    for (int kt = 0; kt < NT1; ++kt) {
        __syncthreads();
        int cur = kt & 1;
        if (kt + 1 < NT1) {
            int k0 = (kt + 1) * 32;
            const bf16* As = A0; int kk = k0;
            if (CONCAT && k0 >= 256) { As = A1; kk = k0 - 256; }
            stage8<128>(As, 256, Abuf + (cur ^ 1) * 8192, tid, m0, kk);
            stage8<256>(B1p, K1, Bbuf + (cur ^ 1) * 16384, tid, 0, k0);
        }
        const char* As = Abuf + cur * 8192;
        const char* Bs = Bbuf + cur * 16384;
        short8 af[4], bfr[4];
#pragma unroll
        for (int mi = 0; mi < 4; ++mi) af[mi] = *(const short8*)(As + offa[mi]);
#pragma unroll
        for (int ni = 0; ni < 4; ++ni) bfr[ni] = *(const short8*)(Bs + offb[ni]);
#pragma unroll
        for (int mi = 0; mi < 4; ++mi)
#pragma unroll
            for (int ni = 0; ni < 4; ++ni)
                acc[mi][ni] = __builtin_amdgcn_mfma_f32_16x16x32_bf16(af[mi], bfr[ni], acc[mi][ni], 0, 0, 0);
    }

    // ---- W2 kc=0 prefetch ----
    int co0 = wid * 32 + c16;
    short8 wf[2][2];
    wf[0][0] = *(const short8*)(W2p + (size_t)co0 * 256 + kg * 8);
    wf[0][1] = *(const short8*)(W2p + (size_t)(co0 + 16) * 256 + kg * 8);

    float bv1[4];
#pragma unroll
    for (int ni = 0; ni < 4; ++ni) bv1[ni] = args.b1[sel][wc * 64 + ni * 16 + c16];
    __syncthreads();   // stage1 reads done; lds becomes h
#pragma unroll
    for (int mi = 0; mi < 4; ++mi)
#pragma unroll
        for (int ni = 0; ni < 4; ++ni) {
            int c = wc * 64 + ni * 16 + c16;
#pragma unroll
            for (int j = 0; j < 4; ++j) {
                int r = wr * 64 + mi * 16 + kg * 4 + j;
                float v = acc[mi][ni][j] + bv1[ni];
                v = v > 0.f ? v : 0.01f * v;
                *(bf16*)(lds + h_off2(r, c)) = f2bf(v);
            }
        }
    __syncthreads();

    // ---- stage2: wave = 32 cols x 128 rows ----
    f32x4 acc2[8][2];
#pragma unroll
    for (int i = 0; i < 8; ++i) {
        acc2[i][0] = (f32x4){0.f, 0.f, 0.f, 0.f};
        acc2[i][1] = (f32x4){0.f, 0.f, 0.f, 0.f};
    }
#pragma unroll
    for (int kc = 0; kc < 8; ++kc) {
        if (kc < 7) {
            wf[(kc + 1) & 1][0] = *(const short8*)(W2p + (size_t)co0 * 256 + (kc + 1) * 32 + kg * 8);
            wf[(kc + 1) & 1][1] = *(const short8*)(W2p + (size_t)(co0 + 16) * 256 + (kc + 1) * 32 + kg * 8);
        }
#pragma unroll
        for (int mi = 0; mi < 8; ++mi) {
            short8 a2 = *(const short8*)(lds + h_off2(mi * 16 + c16, kc * 32 + kg * 8));
            acc2[mi][0] = __builtin_amdgcn_mfma_f32_16x16x32_bf16(a2, wf[kc & 1][0], acc2[mi][0], 0, 0, 0);
            acc2[mi][1] = __builtin_amdgcn_mfma_f32_16x16x32_bf16(a2, wf[kc & 1][1], acc2[mi][1], 0, 0, 0);
        }
    }

    // ---- epilogue: LDS re-transpose -> coalesced stores ----
    bool trans = TRANS0 && (sel == 0);
    float vsq[2] = {0.f, 0.f};
    __syncthreads();   // h dead
    if (trans) {
#pragma unroll
        for (int mi = 0; mi < 8; ++mi)
#pragma unroll
            for (int j2 = 0; j2 < 2; ++j2) {
                int col = co0 + j2 * 16;
#pragma unroll
                for (int j = 0; j < 4; ++j) {
                    float v = acc2[mi][j2][j];
                    vsq[j2] += v * v;
                    int row = mi * 16 + kg * 4 + j;
                    *(bf16*)(lds + col * 256 + ((row * 2) ^ ((col & 7) << 4))) = f2bf(v);
                }
            }
    } else {
        const float* b2p = args.b2[sel];
        float bvo[2];
        bvo[0] = B2OUT ? b2p[co0] : 0.f;
        bvo[1] = B2OUT ? b2p[co0 + 16] : 0.f;
#pragma unroll
        for (int mi = 0; mi < 8; ++mi)
#pragma unroll
            for (int j2 = 0; j2 < 2; ++j2) {
                int col = co0 + j2 * 16;
#pragma unroll
                for (int j = 0; j < 4; ++j) {
                    int row = mi * 16 + kg * 4 + j;
                    *(bf16*)(lds + h_off2(row, col)) = f2bf(acc2[mi][j2][j] + bvo[j2]);
                }
            }
    }
    __syncthreads();
    if (trans) {
        bf16* dst = args.outT[sel];
#pragma unroll
        for (int i = 0; i < 8; ++i) {
            int g = i * 512 + tid;
            int col = g >> 4, rc = g & 15;
            short8 vv = *(const short8*)(lds + col * 256 + ((rc ^ (col & 7)) << 4));
            *(short8*)(dst + (size_t)col * 65536 + m0 + rc * 8) = vv;
        }
        float* cs = (float*)(lds + 65536);
        if (tid < 256) cs[tid] = 0.f;
        __syncthreads();
        atomicAdd(&cs[co0], vsq[0]);
        atomicAdd(&cs[co0 + 16], vsq[1]);
        __syncthreads();
        if (tid < 256)
            atomicAdd(args.nrm[sel] + (int)(m0 >> 14) * 256 + tid, cs[tid]);
    } else {
        bf16* dst = args.outb[sel];
#pragma unroll
        for (int i = 0; i < 8; ++i) {
            int g = i * 512 + tid;
            int row = g >> 5, cc = g & 31;
            short8 vv = *(const short8*)(lds + row * 512 + ((cc ^ (row & 7)) << 4));
            *(short8*)(dst + (size_t)(m0 + row) * 256 + cc * 8) = vv;
        }
    }
}

// ======================================================================
// projconv: out[row,256] = V @ PW(quarter)^T + bias_total + dwconv2(ctmp)
// block = 128 rows = one image line; GEMM with LDS-staged A and B.
// ======================================================================
__launch_bounds__(512, 2)
__global__ void projconv_kernel(const bf16* __restrict__ vbuf, const bf16* __restrict__ PW,
                                const bf16* __restrict__ ctmp,
                                const float* __restrict__ px_b, const float* __restrict__ py_b,
                                const float* __restrict__ peT2, const float* __restrict__ pe_b2,
                                float* __restrict__ outf)
{
    __shared__ __align__(16) char lds[76800];
    float* ldsF = (float*)lds;                       // [64][260] f32 (66560 B), conv phase
    float* ldsW = (float*)(lds + 66560);             // [9][256]  f32
    float* ldsB = (float*)(lds + 75776);             // [256]     f32
    int tid = threadIdx.x;
    int lane = tid & 63, wid = tid >> 6;
    int c16 = lane & 15, kg = lane >> 4;
    int wr = wid >> 2, wc = wid & 3;
    long m0 = (long)blockIdx.y * 128;
    int quarter = (int)(m0 >> 14);
    int y = (int)((m0 & 16383) >> 7);
    char* Abuf = lds;                                // 2 x 8192  (GEMM phase only)
    char* Bbuf = lds + 16384;                        // 2 x 16384 (GEMM phase only)

    f32x4 acc[4][4];
#pragma unroll
    for (int i = 0; i < 4; ++i)
#pragma unroll
        for (int j = 0; j < 4; ++j) acc[i][j] = (f32x4){0.f, 0.f, 0.f, 0.f};

    const bf16* Bq = PW + (size_t)quarter * 65536;

    stage8<128>(vbuf, 256, Abuf, tid, m0, 0);
    stage8<256>(Bq, 256, Bbuf, tid, 0, 0);

    // conv tables (region disjoint from staging: >= 66560)
#pragma unroll
    for (int i = 0; i < 5; ++i) {
        int idx = i * 512 + tid;
        if (idx < 2304) ldsW[idx] = peT2[idx];
    }
    if (tid < 256) ldsB[tid] = (quarter < 2 ? px_b : py_b)[tid] + pe_b2[tid];

    int kb = kg * 16;
    int offa[4], offb[4];
#pragma unroll
    for (int mi = 0; mi < 4; ++mi) {
        int row = wr * 64 + mi * 16 + c16;
        offa[mi] = row * 64 + (kb ^ (((row >> 1) & 3) << 4));
    }
#pragma unroll
    for (int ni = 0; ni < 4; ++ni) {
        int row = wc * 64 + ni * 16 + c16;
        offb[ni] = row * 64 + (kb ^ (((row >> 1) & 3) << 4));
    }

#pragma unroll
    for (int kt = 0; kt < 8; ++kt) {
        __syncthreads();
        int cur = kt & 1;
        if (kt + 1 < 8) {
            int k0 = (kt + 1) * 32;
            stage8<128>(vbuf, 256, Abuf + (cur ^ 1) * 8192, tid, m0, k0);
            stage8<256>(Bq, 256, Bbuf + (cur ^ 1) * 16384, tid, 0, k0);
        }
        const char* As = Abuf + cur * 8192;
        const char* Bs = Bbuf + cur * 16384;
        short8 af[4], bfr[4];
#pragma unroll
        for (int mi = 0; mi < 4; ++mi) af[mi] = *(const short8*)(As + offa[mi]);
#pragma unroll
        for (int ni = 0; ni < 4; ++ni) bfr[ni] = *(const short8*)(Bs + offb[ni]);
#pragma unroll
        for (int mi = 0; mi < 4; ++mi)
#pragma unroll
            for (int ni = 0; ni < 4; ++ni)
                acc[mi][ni] = __builtin_amdgcn_mfma_f32_16x16x32_bf16(af[mi], bfr[ni], acc[mi][ni], 0, 0, 0);
    }

    const bf16* cbase = ctmp + (((size_t)quarter << 14) << 8);
#pragma unroll
    for (int hh = 0; hh < 2; ++hh) {
        __syncthreads();   // prev phase (GEMM staging reads / prev conv) done
        if (wr == hh) {
#pragma unroll
            for (int mi = 0; mi < 4; ++mi)
#pragma unroll
                for (int ni = 0; ni < 4; ++ni) {
                    int col = wc * 64 + ni * 16 + c16;
#pragma unroll
                    for (int j = 0; j < 4; ++j)
                        ldsF[(mi * 16 + kg * 4 + j) * 260 + col] = acc[mi][ni][j];
                }
        }
        __syncthreads();
#pragma unroll
        for (int pass = 0; pass < 4; ++pass) {
            int idx = pass * 512 + tid;          // 0..2047
            int cg = idx & 31, c0 = cg * 8;
            int xl = idx >> 5;                   // 0..63
            int x = hh * 64 + xl;
            float a8[8];
#pragma unroll
            for (int j = 0; j < 8; ++j) a8[j] = ldsB[c0 + j];
#pragma unroll
            for (int dy = -1; dy <= 1; ++dy) {
                int yy = y + dy;
                if (yy < 0 || yy > 127) continue;
#pragma unroll
                for (int dx = -1; dx <= 1; ++dx) {
                    int xx = x + dx;
                    if (xx < 0 || xx > 127) continue;
                    short8 v = *(const short8*)(cbase + (size_t)((yy << 7) + xx) * 256 + c0);
                    const float* wt = ldsW + ((dy + 1) * 3 + dx + 1) * 256 + c0;
#pragma unroll
                    for (int j = 0; j < 8; ++j) a8[j] += wt[j] * bfbits2f(v[j]);
                }
            }
            const float* pf = ldsF + xl * 260 + c0;
#pragma unroll
            for (int j = 0; j < 8; ++j) a8[j] += pf[j];
            float4 o0 = make_float4(a8[0], a8[1], a8[2], a8[3]);
            float4 o1 = make_float4(a8[4], a8[5], a8[6], a8[7]);
            float4* op = (float4*)(outf + (size_t)(m0 + x) * 256 + c0);
            op[0] = o0; op[1] = o1;
        }
    }
}

// ======================================================================
// merged: dwconv1+GELU (blocks 0..2047) | MFMA Gram (blocks 2048..2559)
// ======================================================================
__launch_bounds__(256)
__global__ void convgram_kernel(const bf16* __restrict__ in, const float* __restrict__ wT,
                                const float* __restrict__ bias, bf16* __restrict__ outb,
                                const bf16* __restrict__ qT, const bf16* __restrict__ kT,
                                float* __restrict__ gram)
{
    __shared__ float g[1024];
    int blk = blockIdx.x, tid = threadIdx.x;
    if (blk < 2048) {
        // ---------------- depthwise conv1 + GELU ----------------
        int t = blk * 256 + tid;
        int cg = t & 31;
        int x = (t >> 5) & 127;
        int chunk = (t >> 12) & 31;
        int img = t >> 17;
        int c0 = cg * 8;

        float w[9][8];
#pragma unroll
        for (int k = 0; k < 9; ++k) {
            float4 a = *(const float4*)(wT + k * 256 + c0);
            float4 bq = *(const float4*)(wT + k * 256 + c0 + 4);
            w[k][0] = a.x; w[k][1] = a.y; w[k][2] = a.z; w[k][3] = a.w;
            w[k][4] = bq.x; w[k][5] = bq.y; w[k][6] = bq.z; w[k][7] = bq.w;
        }
        float bs[8];
        {
            float4 a = *(const float4*)(bias + c0);
            float4 bq = *(const float4*)(bias + c0 + 4);
            bs[0] = a.x; bs[1] = a.y; bs[2] = a.z; bs[3] = a.w;
            bs[4] = bq.x; bs[5] = bq.y; bs[6] = bq.z; bs[7] = bq.w;
        }
        const short8 z = (short8){0, 0, 0, 0, 0, 0, 0, 0};
        bool xm = x > 0, xp = x < 127;
        int y0 = chunk * 4;

        for (int yi = 0; yi < 4; ++yi) {
            int y = y0 + yi;
            float acc[8];
#pragma unroll
            for (int j = 0; j < 8; ++j) acc[j] = bs[j];
#pragma unroll
            for (int ky = -1; ky <= 1; ++ky) {
                int yy = y + ky;
                if (yy < 0 || yy > 127) continue;
                const bf16* rp = in + ((((size_t)img << 14) + (yy << 7) + x) << 8) + c0;
                short8 vm = xm ? *(const short8*)(rp - 256) : z;
                short8 vc = *(const short8*)(rp);
                short8 vp = xp ? *(const short8*)(rp + 256) : z;
                int k0 = (ky + 1) * 3;
#pragma unroll
                for (int j = 0; j < 8; ++j) {
                    acc[j] += w[k0 + 0][j] * bfbits2f(vm[j]);
                    acc[j] += w[k0 + 1][j] * bfbits2f(vc[j]);
                    acc[j] += w[k0 + 2][j] * bfbits2f(vp[j]);
                }
            }
            size_t base = ((((size_t)img << 14) + (y << 7) + x) << 8) + c0;
            short8 p;
#pragma unroll
            for (int j = 0; j < 8; ++j) {
                float a = acc[j];
                a = 0.5f * a * (1.0f + erff(a * 0.70710678118654752f));
                p[j] = f2bfbits(a);
            }
            *(short8*)(outb + base) = p;
        }
    } else {
        // ---------------- MFMA Gram ----------------
        int bid = blk - 2048;
        int ns = bid & 15, h = (bid >> 4) & 7, b = (bid >> 7) & 1, pair = bid >> 8;
        int lane = tid & 63, w = tid >> 6;
        long krow = pair ? (long)b * 16384 : (long)(32768 + b * 16384);
        long qrow = pair ? (long)(32768 + b * 16384) : (long)b * 16384;
        long nb = (long)ns * 1024 + w * 256 + (lane >> 4) * 8;
        const bf16* Kp = kT + krow + nb;
        const bf16* Qp = qT + qrow + nb;
        int ch = h * 32 + (lane & 15);

        f32x4 acc[2][2];
#pragma unroll
        for (int i = 0; i < 2; ++i)
#pragma unroll
            for (int j = 0; j < 2; ++j) acc[i][j] = (f32x4){0.f, 0.f, 0.f, 0.f};

        for (int it = 0; it < 8; ++it) {
            short8 af[2], bfr[2];
#pragma unroll
            for (int mi = 0; mi < 2; ++mi)
                af[mi] = *(const short8*)(Kp + (size_t)(ch + mi * 16) * 65536 + it * 32);
#pragma unroll
            for (int ni = 0; ni < 2; ++ni)
                bfr[ni] = *(const short8*)(Qp + (size_t)(ch + ni * 16) * 65536 + it * 32);
#pragma unroll
            for (int mi = 0; mi < 2; ++mi)
#pragma unroll
                for (int ni = 0; ni < 2; ++ni)
                    acc[mi][ni] = __builtin_amdgcn_mfma_f32_16x16x32_bf16(af[mi], bfr[ni], acc[mi][ni], 0, 0, 0);
        }

#pragma unroll
        for (int k = 0; k < 4; ++k) g[tid + k * 256] = 0.f;
        __syncthreads();
#pragma unroll
        for (int mi = 0; mi < 2; ++mi)
#pragma unroll
            for (int ni = 0; ni < 2; ++ni) {
                int e = ni * 16 + (lane & 15);
#pragma unroll
                for (int j = 0; j < 4; ++j) {
                    int d = mi * 16 + (lane >> 4) * 4 + j;
                    atomicAdd(&g[d * 32 + e], acc[mi][ni][j]);
                }
            }
        __syncthreads();
        float* gp = gram + ((size_t)((pair * 2 + b) * 8 + h)) * 1024;
#pragma unroll
        for (int k = 0; k < 4; ++k)
            atomicAdd(gp + tid + k * 256, g[tid + k * 256]);
    }
}

// ======================================================================
// softmax + fold attention into project-out weights
// ======================================================================
__launch_bounds__(256)
__global__ void attn_pw_kernel(const float* __restrict__ gram, const float* __restrict__ norm2,
                               const float* __restrict__ rsx, const float* __restrict__ rsy,
                               const float* __restrict__ pxw, const float* __restrict__ pyw,
                               bf16* __restrict__ PW)
{
    int bid = blockIdx.x;
    int h = bid & 7, b = (bid >> 3) & 1, pair = bid >> 4;
    const float* G = gram + ((size_t)((pair * 2 + b) * 8 + h)) * 1024;
    const float* nk2 = norm2 + (pair ? (4 + b) : (6 + b)) * 256 + h * 32;
    const float* nq2 = norm2 + (pair ? (2 + b) : (0 + b)) * 256 + h * 32;
    float rs = (pair ? rsy : rsx)[h];
    __shared__ float attn[32][32];
    int t = threadIdx.x;
    if (t < 32) {
        int d = t;
        float nk = fmaxf(sqrtf(nk2[d]), 1e-12f);
        float row[32];
        float mx = -3.4e38f;
#pragma unroll
        for (int e = 0; e < 32; ++e) {
            float nq = fmaxf(sqrtf(nq2[e]), 1e-12f);
            float L = G[d * 32 + e] / (nk * nq) * rs;
            row[e] = L;
            mx = fmaxf(mx, L);
        }
        float sum = 0.f;
#pragma unroll
        for (int e = 0; e < 32; ++e) { row[e] = expf(row[e] - mx); sum += row[e]; }
        float inv = 1.0f / sum;
#pragma unroll
        for (int e = 0; e < 32; ++e) attn[d][e] = row[e] * inv;
    }
    __syncthreads();
    const float* pw = pair ? pyw : pxw;
    int o = t;
    float wrow[32];
#pragma unroll
    for (int d2 = 0; d2 < 32; ++d2) wrow[d2] = pw[o * 256 + h * 32 + d2];
    bf16* dst = PW + ((size_t)(pair * 2 + b) * 256 + o) * 256 + h * 32;
#pragma unroll
    for (int e = 0; e < 32; ++e) {
        float sv = 0.f;
#pragma unroll
        for (int d2 = 0; d2 < 32; ++d2) sv += wrow[d2] * attn[d2][e];
        dst[e] = f2bf(sv);
    }
}

// ======================================================================
// launch
// ======================================================================
extern "C" void kernel_launch(void* const* d_in, const int* in_sizes, int n_in,
                              void* d_out, int out_size, void* d_ws, size_t ws_size,
                              hipStream_t stream)
{
    const float* x_in  = (const float*)d_in[0];
    const float* y_in  = (const float*)d_in[1];
    const float* fx_w1 = (const float*)d_in[2];
    const float* fx_b1 = (const float*)d_in[3];
    const float* fx_w2 = (const float*)d_in[4];
    const float* fx_b2 = (const float*)d_in[5];
    const float* fy_w1 = (const float*)d_in[6];
    const float* fy_b1 = (const float*)d_in[7];
    const float* fy_w2 = (const float*)d_in[8];
    const float* fy_b2 = (const float*)d_in[9];
    const float* q_w1  = (const float*)d_in[10];
    const float* q_b1  = (const float*)d_in[11];
    const float* q_w2  = (const float*)d_in[12];
    const float* k_w1  = (const float*)d_in[13];
    const float* k_b1  = (const float*)d_in[14];
    const float* k_w2  = (const float*)d_in[15];
    const float* v_w1  = (const float*)d_in[16];
    const float* v_b1  = (const float*)d_in[17];
    const float* v_w2  = (const float*)d_in[18];
    const float* rescale_x = (const float*)d_in[19];
    const float* rescale_y = (const float*)d_in[20];
    const float* px_w  = (const float*)d_in[21];
    const float* px_b  = (const float*)d_in[22];
    const float* py_w  = (const float*)d_in[23];
    const float* py_b  = (const float*)d_in[24];
    const float* pe_w1 = (const float*)d_in[25];
    const float* pe_b1 = (const float*)d_in[26];
    const float* pe_w2 = (const float*)d_in[27];
    const float* pe_b2 = (const float*)d_in[28];

    char* ws = (char*)d_ws;
    const size_t NB = 16777216;
    bf16* xbf  = (bf16*)(ws + 0 * NB);    // [xb | yb] adjacent (65536 rows)
    bf16* ybf  = (bf16*)(ws + 1 * NB);
    bf16* fkx  = (bf16*)(ws + 2 * NB);    // [fkx | fky]; reused as ctmp after k-MLP
    bf16* fky  = (bf16*)(ws + 3 * NB);
    bf16* vbuf = (bf16*)(ws + 4 * NB);    // 65536 rows [vx_b0,vx_b1,vy_b0,vy_b1]
    bf16* qT   = (bf16*)(ws + 6 * NB);    // [256][65536] channel-major
    bf16* kT   = (bf16*)(ws + 8 * NB);
    char* wreg = ws + 10 * NB;
    bf16* w_fx1 = (bf16*)(wreg + 0);
    bf16* w_fx2 = (bf16*)(wreg + 262144);
    bf16* w_fy1 = (bf16*)(wreg + 393216);
    bf16* w_fy2 = (bf16*)(wreg + 655360);
    bf16* w_q1  = (bf16*)(wreg + 786432);
    bf16* w_q2  = (bf16*)(wreg + 917504);
    bf16* w_k1  = (bf16*)(wreg + 1048576);
    bf16* w_k2  = (bf16*)(wreg + 1179648);
    bf16* w_v1  = (bf16*)(wreg + 1310720);
    bf16* w_v2  = (bf16*)(wreg + 1441792);
    float* gram  = (float*)(wreg + 1572864);             // 128 KB
    float* norm2 = (float*)(wreg + 1572864 + 131072);    // 8 KB
    bf16* PW     = (bf16*)(wreg + 1572864 + 139264);     // 512 KB
    float* peT1  = (float*)(wreg + 1572864 + 139264 + 524288);
    float* peT2  = (float*)(wreg + 1572864 + 139264 + 524288 + 9216);
    bf16* ctmp   = fkx;                    // 65536-row conv temp (fk dead by then)

    float* outx = (float*)d_out;           // rows 0..32767 = x, 32768.. = y

    // ---- prep ----
    PrepArgs pa;
    pa.x = x_in; pa.y = y_in; pa.xb = xbf; pa.yb = ybf;
    const float* ws_src[10] = {fx_w1, fx_w2, fy_w1, fy_w2, q_w1, q_w2, k_w1, k_w2, v_w1, v_w2};
    bf16* ws_dst[10] = {w_fx1, w_fx2, w_fy1, w_fy2, w_q1, w_q2, w_k1, w_k2, w_v1, w_v2};
    int nblk[10] = {128, 64, 128, 64, 64, 64, 64, 64, 64, 64};
    for (int i = 0; i < 10; ++i) { pa.wsrc[i] = ws_src[i]; pa.wdst[i] = ws_dst[i]; pa.wblk[i] = nblk[i]; }
    pa.pw1 = pe_w1; pa.pw2 = pe_w2; pa.t1 = peT1; pa.t2 = peT2;
    pa.zero = (float4*)gram;
    prep_kernel<<<9012, 256, 0, stream>>>(pa);

    // ---- fusion MLPs (sel: fx, fy) ----
    MlpArgs fa = {};
    fa.B1[0] = w_fx1; fa.B1[1] = w_fy1; fa.b1[0] = fx_b1; fa.b1[1] = fy_b1;
    fa.W2[0] = w_fx2; fa.W2[1] = w_fy2; fa.b2[0] = fx_b2; fa.b2[1] = fy_b2;
    fa.outb[0] = fkx; fa.outb[1] = fky;
    mlp_kernel<512, true, true, false><<<dim3(2, 256), 512, 0, stream>>>(xbf, ybf, fa);

    // ---- q/v MLPs (sel: q -> qT+norm, v -> vbuf); shared A = [x;y] ----
    MlpArgs qa = {};
    qa.B1[0] = w_q1; qa.B1[1] = w_v1; qa.b1[0] = q_b1; qa.b1[1] = v_b1;
    qa.W2[0] = w_q2; qa.W2[1] = w_v2;
    qa.outT[0] = qT; qa.nrm[0] = norm2;
    qa.outb[1] = vbuf;
    mlp_kernel<256, false, false, true><<<dim3(2, 512), 512, 0, stream>>>(xbf, nullptr, qa);

    // ---- k MLP over [fkx;fky] -> kT + norm2[4..7] ----
    MlpArgs ka = {};
    ka.B1[0] = w_k1; ka.b1[0] = k_b1; ka.W2[0] = w_k2;
    ka.outT[0] = kT; ka.nrm[0] = norm2 + 1024;
    mlp_kernel<256, false, false, true><<<dim3(1, 512), 512, 0, stream>>>(fkx, nullptr, ka);

    // ---- conv1(+GELU) and Gram in one dispatch (independent work) ----
    convgram_kernel<<<2560, 256, 0, stream>>>(vbuf, peT1, pe_b1, ctmp, qT, kT, gram);

    // ---- softmax + PW fold ----
    attn_pw_kernel<<<32, 256, 0, stream>>>(gram, norm2, rescale_x, rescale_y, px_w, py_w, PW);

    // ---- project-out + conv2 + biases, single pass over d_out ----
    projconv_kernel<<<dim3(1, 512), 512, 0, stream>>>(vbuf, PW, ctmp, px_b, py_b,
                                                      peT2, pe_b2, outx);
}